// Round 1
// baseline (758.579 us; speedup 1.0000x reference)
//
#include <hip/hip_runtime.h>
#include <hip/hip_bf16.h>
#include <stdint.h>

// Problem: out[b,s,o] = sum_i x[b,s,i] * W[o,i],  W = (V * (s*mask)) @ U^T
// Factored: Y = (x @ U) * (s*mask)  [16384, 512];  out = Y @ V^T  [16384, 4096]
// M = 8*2048 = 16384, IN_F = 4096, OUT_F = 4096, KMAX = 512.

typedef __attribute__((ext_vector_type(8))) short short8;   // 8 bf16 = 4 VGPRs (MFMA A/B frag)
typedef __attribute__((ext_vector_type(4))) float f32x4;    // MFMA C/D frag
typedef __attribute__((ext_vector_type(4))) unsigned int uint4v;

// ---- helpers ----------------------------------------------------------------

// round-to-nearest-even f32 -> bf16 bits
__device__ __forceinline__ unsigned short f2bf_rne(float f) {
    unsigned int u = __builtin_bit_cast(unsigned int, f);
    unsigned int r = u + 0x7fffu + ((u >> 16) & 1u);
    return (unsigned short)(r >> 16);
}

// pack two f32 -> two bf16 (round-half-up; error negligible vs 2% tolerance, cheaper VALU)
__device__ __forceinline__ unsigned int pk2bf(float a, float b) {
    unsigned int ua = __builtin_bit_cast(unsigned int, a);
    unsigned int ub = __builtin_bit_cast(unsigned int, b);
    ua = (ua + 0x8000u) >> 16;
    ub = (ub + 0x8000u) & 0xffff0000u;
    return ua | ub;
}

// async global->LDS, 16 bytes/lane; LDS dest must be wave-uniform base (+lane*16 implicit)
__device__ __forceinline__ void async_load16(const void* g, void* l) {
    __builtin_amdgcn_global_load_lds(
        (const __attribute__((address_space(1))) unsigned int*)g,
        (__attribute__((address_space(3))) unsigned int*)l,
        16, 0, 0);
}

// ---- prep kernels -----------------------------------------------------------

// Ut[n][k] = bf16( U[k][n] * s[n] * mask[n] ),  U: [4096,512] f32 -> Ut: [512,4096] bf16
__global__ void prep_u(const float* __restrict__ U, const float* __restrict__ S,
                       const int* __restrict__ Mask, unsigned short* __restrict__ Ut) {
    __shared__ float t[32][33];
    const int tx = threadIdx.x, ty = threadIdx.y;       // (32, 8)
    const int n0 = blockIdx.x * 32, k0 = blockIdx.y * 32;
#pragma unroll
    for (int i = 0; i < 4; ++i)
        t[ty + i * 8][tx] = U[(size_t)(k0 + ty + i * 8) * 512 + n0 + tx];
    __syncthreads();
#pragma unroll
    for (int i = 0; i < 4; ++i) {
        int n = n0 + ty + i * 8;
        float sm = S[n] * (Mask[n] != 0 ? 1.0f : 0.0f);
        Ut[(size_t)n * 4096 + k0 + tx] = f2bf_rne(t[tx][ty + i * 8] * sm);
    }
}

// Vb = bf16(V), elementwise, 4096*512 = 2M elems, 4/thread
__global__ void prep_v(const float* __restrict__ V, unsigned short* __restrict__ Vb) {
    int i = blockIdx.x * blockDim.x + threadIdx.x;      // 0..524287
    float4 f = ((const float4*)V)[i];
    ushort4 o;
    o.x = f2bf_rne(f.x); o.y = f2bf_rne(f.y);
    o.z = f2bf_rne(f.z); o.w = f2bf_rne(f.w);
    ((ushort4*)Vb)[i] = o;
}

// ---- GEMM1: Y[16384,512] = bf16( x[16384,4096](f32) @ Ut[512,4096]^T ) ------
// 128x128 tile, BK=64, 256 threads (4 waves, 64x64/wave), mfma 16x16x32 bf16.
// LDS layout: [kc=BK/8][row=128][8 bf16] -> chunk index c = kc*128 + row.
__global__ __launch_bounds__(256, 2)
void gemm1_xu(const float* __restrict__ X, const unsigned short* __restrict__ Ut,
              unsigned short* __restrict__ Y) {
    const int tid  = threadIdx.x;
    const int lane = tid & 63;
    const int w    = tid >> 6;
    const int ln   = lane & 15;
    const int quad = lane >> 4;
    const int m0 = blockIdx.y * 128;
    const int n0 = blockIdx.x * 128;
    const int wm = (w >> 1) * 64;
    const int wn = (w & 1) * 64;

    __shared__ short8 As[1024];   // 16 KiB
    __shared__ short8 Bs[1024];   // 16 KiB

    f32x4 acc[4][4] = {};

    for (int kt = 0; kt < 4096; kt += 64) {
        __syncthreads();
        // B tile (bf16, direct-to-LDS): rows n0..n0+127 of Ut, k in [kt, kt+64)
#pragma unroll
        for (int i = 0; i < 4; ++i) {
            int cbase = i * 256 + w * 64;           // wave-uniform
            int c = cbase + lane;
            int kc = c >> 7, n = c & 127;
            async_load16(Ut + (size_t)(n0 + n) * 4096 + kt + kc * 8, (void*)&Bs[cbase]);
        }
        // A tile (f32 -> bf16 cvt): rows m0..m0+127 of x
#pragma unroll
        for (int i = 0; i < 4; ++i) {
            int c = i * 256 + tid;
            int kc = c >> 7, m = c & 127;
            const float* src = X + (size_t)(m0 + m) * 4096 + kt + kc * 8;
            float4 f0 = *(const float4*)(src);
            float4 f1 = *(const float4*)(src + 4);
            uint4v p;
            p.x = pk2bf(f0.x, f0.y); p.y = pk2bf(f0.z, f0.w);
            p.z = pk2bf(f1.x, f1.y); p.w = pk2bf(f1.z, f1.w);
            As[c] = __builtin_bit_cast(short8, p);
        }
        __syncthreads();
#pragma unroll
        for (int ks = 0; ks < 2; ++ks) {
            const int kc = ks * 4 + quad;
            short8 a[4], b[4];
#pragma unroll
            for (int t = 0; t < 4; ++t) {
                a[t] = As[kc * 128 + wm + t * 16 + ln];
                b[t] = Bs[kc * 128 + wn + t * 16 + ln];
            }
#pragma unroll
            for (int mt = 0; mt < 4; ++mt)
#pragma unroll
                for (int nt = 0; nt < 4; ++nt)
                    acc[mt][nt] = __builtin_amdgcn_mfma_f32_16x16x32_bf16(
                        a[mt], b[nt], acc[mt][nt], 0, 0, 0);
        }
    }
    // epilogue: C/D layout col = ln, row = quad*4 + r (m89-verified)
#pragma unroll
    for (int mt = 0; mt < 4; ++mt)
#pragma unroll
        for (int nt = 0; nt < 4; ++nt) {
            int col = n0 + wn + nt * 16 + ln;
#pragma unroll
            for (int r = 0; r < 4; ++r) {
                int row = m0 + wm + mt * 16 + quad * 4 + r;
                Y[(size_t)row * 512 + col] = f2bf_rne(acc[mt][nt][r]);
            }
        }
}

// ---- GEMM2: out[16384,4096](f32) = Y[16384,512] @ Vb[4096,512]^T ------------
__global__ __launch_bounds__(256, 2)
void gemm2_yv(const unsigned short* __restrict__ Y, const unsigned short* __restrict__ Vb,
              float* __restrict__ Out) {
    const int tid  = threadIdx.x;
    const int lane = tid & 63;
    const int w    = tid >> 6;
    const int ln   = lane & 15;
    const int quad = lane >> 4;
    const int m0 = blockIdx.y * 128;
    const int n0 = blockIdx.x * 128;
    const int wm = (w >> 1) * 64;
    const int wn = (w & 1) * 64;

    __shared__ short8 As[1024];
    __shared__ short8 Bs[1024];

    f32x4 acc[4][4] = {};

    for (int kt = 0; kt < 512; kt += 64) {
        __syncthreads();
#pragma unroll
        for (int i = 0; i < 4; ++i) {
            int cbase = i * 256 + w * 64;
            int c = cbase + lane;
            int kc = c >> 7, r = c & 127;
            async_load16(Y  + (size_t)(m0 + r) * 512 + kt + kc * 8, (void*)&As[cbase]);
            async_load16(Vb + (size_t)(n0 + r) * 512 + kt + kc * 8, (void*)&Bs[cbase]);
        }
        __syncthreads();
#pragma unroll
        for (int ks = 0; ks < 2; ++ks) {
            const int kc = ks * 4 + quad;
            short8 a[4], b[4];
#pragma unroll
            for (int t = 0; t < 4; ++t) {
                a[t] = As[kc * 128 + wm + t * 16 + ln];
                b[t] = Bs[kc * 128 + wn + t * 16 + ln];
            }
#pragma unroll
            for (int mt = 0; mt < 4; ++mt)
#pragma unroll
                for (int nt = 0; nt < 4; ++nt)
                    acc[mt][nt] = __builtin_amdgcn_mfma_f32_16x16x32_bf16(
                        a[mt], b[nt], acc[mt][nt], 0, 0, 0);
        }
    }
#pragma unroll
    for (int mt = 0; mt < 4; ++mt)
#pragma unroll
        for (int nt = 0; nt < 4; ++nt) {
            int col = n0 + wn + nt * 16 + ln;
#pragma unroll
            for (int r = 0; r < 4; ++r) {
                int row = m0 + wm + mt * 16 + quad * 4 + r;
                Out[(size_t)row * 4096 + col] = acc[mt][nt][r];
            }
        }
}

// ---- launch -----------------------------------------------------------------

extern "C" void kernel_launch(void* const* d_in, const int* in_sizes, int n_in,
                              void* d_out, int out_size, void* d_ws, size_t ws_size,
                              hipStream_t stream) {
    const float* X    = (const float*)d_in[0];   // [8,2048,4096]
    const float* U    = (const float*)d_in[1];   // [4096,512]
    const float* V    = (const float*)d_in[2];   // [4096,512]
    const float* S    = (const float*)d_in[3];   // [512]
    const int*   Mask = (const int*)d_in[4];     // [512] (bool -> int32 assumed)

    char* ws = (char*)d_ws;
    unsigned short* Ut = (unsigned short*)ws;                               // 4 MiB
    unsigned short* Vb = (unsigned short*)(ws + (size_t)512 * 4096 * 2);    // 4 MiB
    unsigned short* Yb = (unsigned short*)(ws + (size_t)512 * 4096 * 4);    // 16.8 MiB
    float* Out = (float*)d_out;

    prep_u<<<dim3(16, 128), dim3(32, 8), 0, stream>>>(U, S, Mask, Ut);
    prep_v<<<dim3(1024), dim3(512), 0, stream>>>(V, Vb);
    gemm1_xu<<<dim3(4, 128), dim3(256), 0, stream>>>(X, Ut, Yb);
    gemm2_yv<<<dim3(32, 128), dim3(256), 0, stream>>>(Yb, Vb, Out);
}